// Round 4
// baseline (211.583 us; speedup 1.0000x reference)
//
#include <hip/hip_runtime.h>
#include <hip/hip_fp16.h>

// SSIM loss, fused. fp32 in [16,3,512,512], fp32 scalar out.
// Block = 256 thr, stripe 64 wide x 256 tall, processed in 4 steps of 64 rows.
// Per step: restage 74 h-blurred rows (5 quantities, fp16) into flat LDS
// (47.4 KB -> 3 blocks/CU, grid 768 = fully co-resident), then vblur+SSIM
// with 4col x 4row per thread using ds_read_b64 (kills the LDS-pipe
// bottleneck diagnosed in round 3: 70 ds_read_u16/thread -> 70 ds_read_b64
// per 4x the pixels). fp32 math, fp16 staging (round-3-validated precision).

#define WIDTH  512
#define HEIGHT 512
#define TW 64
#define SH 256            // stripe height per block
#define STEP 64           // rows per step
#define NSTEP (SH / STEP) // 4
#define BR 74             // staged rows per step (64 + 10 halo)
#define TILES_X 8
#define TILES_Y (HEIGHT / SH)   // 2
#define PLANES 48
#define NBLK (TILES_X * TILES_Y * PLANES)   // 768
#define NPIXF 12582912.0f

__global__ __launch_bounds__(256, 3)
void ssim_main(const float* __restrict__ pred,
               const float* __restrict__ tgt,
               float* __restrict__ partial) {
    __shared__ __half s_h[BR][5][TW];   // 47360 B
    __shared__ float s_red[4];

    const int tid = threadIdx.x;
    const int x0 = blockIdx.x * TW;
    const int y0 = blockIdx.y * SH;
    const size_t plane_off = (size_t)blockIdx.z * (WIDTH * HEIGHT);
    const float* P = pred + plane_off;
    const float* T = tgt + plane_off;
    const bool x_int = (x0 >= 8) && (x0 + TW + 8 <= WIDTH);

    // Normalized 1D Gaussian (k=11, sigma=1.5); matches reference to ~3e-7.
    const float w[11] = {0.00102839f, 0.00759881f, 0.03600077f, 0.10936069f,
                         0.21300566f, 0.26601168f, 0.21300566f, 0.10936069f,
                         0.03600077f, 0.00759881f, 0.00102839f};

    const int cg2 = tid & 15;          // phase-2 col-group (4 cols)
    const int rg2 = tid >> 4;          // phase-2 row-group (4 rows)

    float lsum = 0.f;

    for (int s = 0; s < NSTEP; ++s) {
        const int base_y = y0 + STEP * s - 5;   // buffer row 0 == this gy

        // ---- Phase 1: hblur 74 rows x 16 col-groups = 1184 items ----
        for (int it = tid; it < BR * 16; it += 256) {
            const int row = it >> 4;
            const int cg  = it & 15;
            const int gy  = base_y + row;
            float p[20], t[20];
            if ((unsigned)gy >= (unsigned)HEIGHT) {
#pragma unroll
                for (int i = 0; i < 20; ++i) { p[i] = 0.f; t[i] = 0.f; }
            } else {
                const float* Pr = P + (size_t)gy * WIDTH;
                const float* Tr = T + (size_t)gy * WIDTH;
                const int gx0 = x0 + cg * 4 - 8;
                if (x_int) {
                    const float4* Pq = (const float4*)(Pr + gx0);
                    const float4* Tq = (const float4*)(Tr + gx0);
#pragma unroll
                    for (int v = 0; v < 5; ++v) {
                        float4 a = Pq[v], b = Tq[v];
                        p[4*v+0] = a.x; p[4*v+1] = a.y; p[4*v+2] = a.z; p[4*v+3] = a.w;
                        t[4*v+0] = b.x; t[4*v+1] = b.y; t[4*v+2] = b.z; t[4*v+3] = b.w;
                    }
                } else {
#pragma unroll
                    for (int i = 0; i < 20; ++i) {
                        int gx = gx0 + i;
                        bool ok = (unsigned)gx < (unsigned)WIDTH;
                        p[i] = ok ? Pr[gx] : 0.f;
                        t[i] = ok ? Tr[gx] : 0.f;
                    }
                }
            }
            float ap[4]  = {0,0,0,0}, at[4]  = {0,0,0,0}, app[4] = {0,0,0,0},
                  att[4] = {0,0,0,0}, apt[4] = {0,0,0,0};
#pragma unroll
            for (int m = 3; m <= 16; ++m) {
                float pm = p[m], tm = t[m];
                float ppm = pm * pm, ttm = tm * tm, ptm = pm * tm;
#pragma unroll
                for (int k = 0; k < 4; ++k) {
                    int i = m - 3 - k;
                    if (i >= 0 && i <= 10) {
                        float wi = w[i];
                        ap[k]  = fmaf(wi, pm,  ap[k]);
                        at[k]  = fmaf(wi, tm,  at[k]);
                        app[k] = fmaf(wi, ppm, app[k]);
                        att[k] = fmaf(wi, ttm, att[k]);
                        apt[k] = fmaf(wi, ptm, apt[k]);
                    }
                }
            }
            __half* dst = &s_h[row][0][cg * 4];
            ((__half2*)(dst        ))[0] = __floats2half2_rn(ap[0],  ap[1]);
            ((__half2*)(dst        ))[1] = __floats2half2_rn(ap[2],  ap[3]);
            ((__half2*)(dst + 1*TW ))[0] = __floats2half2_rn(at[0],  at[1]);
            ((__half2*)(dst + 1*TW ))[1] = __floats2half2_rn(at[2],  at[3]);
            ((__half2*)(dst + 2*TW ))[0] = __floats2half2_rn(app[0], app[1]);
            ((__half2*)(dst + 2*TW ))[1] = __floats2half2_rn(app[2], app[3]);
            ((__half2*)(dst + 3*TW ))[0] = __floats2half2_rn(att[0], att[1]);
            ((__half2*)(dst + 3*TW ))[1] = __floats2half2_rn(att[2], att[3]);
            ((__half2*)(dst + 4*TW ))[0] = __floats2half2_rn(apt[0], apt[1]);
            ((__half2*)(dst + 4*TW ))[1] = __floats2half2_rn(apt[2], apt[3]);
        }
        __syncthreads();

        // ---- Phase 2: vblur + SSIM, 4 cols x 4 rows per thread ----
        // Output local rows 4*rg2 .. +3 use buffer rows 4*rg2 .. 4*rg2+13.
        float acc[5][4][4];
#pragma unroll
        for (int q = 0; q < 5; ++q)
#pragma unroll
            for (int r = 0; r < 4; ++r)
#pragma unroll
                for (int c = 0; c < 4; ++c) acc[q][r][c] = 0.f;

        const __half* pbase = &s_h[rg2 * 4][0][cg2 * 4];
#pragma unroll
        for (int q = 0; q < 5; ++q) {
#pragma unroll
            for (int m = 0; m < 14; ++m) {
                const __half2* pp = (const __half2*)(pbase + (size_t)m * (5 * TW) + q * TW);
                float2 fa = __half22float2(pp[0]);
                float2 fb = __half22float2(pp[1]);
                float h0 = fa.x, h1 = fa.y, h2 = fb.x, h3 = fb.y;
#pragma unroll
                for (int r = 0; r < 4; ++r) {
                    int i = m - r;
                    if (i >= 0 && i <= 10) {
                        float wi = w[i];
                        acc[q][r][0] = fmaf(wi, h0, acc[q][r][0]);
                        acc[q][r][1] = fmaf(wi, h1, acc[q][r][1]);
                        acc[q][r][2] = fmaf(wi, h2, acc[q][r][2]);
                        acc[q][r][3] = fmaf(wi, h3, acc[q][r][3]);
                    }
                }
            }
        }

#pragma unroll
        for (int r = 0; r < 4; ++r)
#pragma unroll
            for (int c = 0; c < 4; ++c) {
                float mp = acc[0][r][c], mt = acc[1][r][c];
                float mp2 = mp * mp, mt2 = mt * mt, mpt = mp * mt;
                float sp  = fmaxf(acc[2][r][c] - mp2, 0.f);
                float st  = fmaxf(acc[3][r][c] - mt2, 0.f);
                float spt = acc[4][r][c] - mpt;
                float num = (2.f * mpt + 1e-4f) * (2.f * spt + 9e-4f);
                float den = (mp2 + mt2 + 1e-4f) * (sp + st + 9e-4f);
                lsum += __fdividef(num, den);
            }
        __syncthreads();   // buffer reused next step
    }

    // ---- Block reduction -> one partial per block ----
#pragma unroll
    for (int off = 32; off > 0; off >>= 1) lsum += __shfl_down(lsum, off);
    if ((tid & 63) == 0) s_red[tid >> 6] = lsum;
    __syncthreads();
    if (tid == 0) {
        partial[(blockIdx.z * TILES_Y + blockIdx.y) * TILES_X + blockIdx.x] =
            s_red[0] + s_red[1] + s_red[2] + s_red[3];
    }
}

__global__ __launch_bounds__(256)
void ssim_final(const float* __restrict__ partial, float* __restrict__ out) {
    __shared__ float s_red[4];
    float s = 0.f;
    for (int i = threadIdx.x; i < NBLK; i += 256) s += partial[i];
#pragma unroll
    for (int off = 32; off > 0; off >>= 1) s += __shfl_down(s, off);
    if ((threadIdx.x & 63) == 0) s_red[threadIdx.x >> 6] = s;
    __syncthreads();
    if (threadIdx.x == 0) {
        float total = s_red[0] + s_red[1] + s_red[2] + s_red[3];
        out[0] = 1.0f - total / NPIXF;
    }
}

extern "C" void kernel_launch(void* const* d_in, const int* in_sizes, int n_in,
                              void* d_out, int out_size, void* d_ws, size_t ws_size,
                              hipStream_t stream) {
    const float* pred = (const float*)d_in[0];
    const float* tgt  = (const float*)d_in[1];
    float* partial = (float*)d_ws;   // NBLK floats, fully rewritten each call

    dim3 grid(TILES_X, TILES_Y, PLANES);
    ssim_main<<<grid, dim3(256), 0, stream>>>(pred, tgt, partial);
    ssim_final<<<1, dim3(256), 0, stream>>>(partial, (float*)d_out);
}